// Round 2
// baseline (6022.213 us; speedup 1.0000x reference)
//
#include <hip/hip_runtime.h>
#include <stdint.h>
#include <math.h>

// ---------------------------------------------------------------------------
// Transformer forward, MI355X. Mixed precision: bf16 MFMA operands, fp32
// accum, fp32 residual stream kept in d_out.
// GEMM form: C[M,N] = A[M,K] (row-major bf16) x Bt[N,K]^T (pre-transposed
// bf16 weights). Both operands K-major -> identical LDS staging via
// global_load_lds(width=16) with pre-swizzled global source addresses.
// Token dimension processed in chunks sized to fit ws_size (per-batch-row
// independence: attention only mixes within a 64-token row).
// ---------------------------------------------------------------------------

#define LAYERS 6
#define BATCH  2048
#define SEQ    64
#define DMODEL 256
#define NHEAD  8
#define DHEAD  64
#define INNERD 512
#define FFDIM  1024
#define VOCAB  100
#define MTOK   (BATCH*SEQ)   // 131072

typedef unsigned short u16;
typedef __attribute__((ext_vector_type(4))) float f32x4;
typedef __attribute__((ext_vector_type(4))) short s16x4;
typedef __attribute__((ext_vector_type(8))) short s16x8;

__device__ inline u16 f2bf(float f){
  union { float f; unsigned int u; } x; x.f = f;
  unsigned int u = x.u;
  return (u16)((u + 0x7fffu + ((u >> 16) & 1u)) >> 16);
}

__device__ inline void gload16(const void* g, void* l){
  __builtin_amdgcn_global_load_lds(
      (const __attribute__((address_space(1))) unsigned int*)g,
      (__attribute__((address_space(3))) unsigned int*)l, 16, 0, 0);
}

__device__ inline f32x4 mfma16(s16x8 a, s16x8 b, f32x4 c){
  return __builtin_amdgcn_mfma_f32_16x16x32_bf16(a, b, c, 0, 0, 0);
}

// two ds_read_b64 -> one 8-elem fragment (indices in u16 units)
__device__ inline s16x8 ldfrag(const u16* lds, int i0, int i1){
  s16x4 lo = *(const s16x4*)(lds + i0);
  s16x4 hi = *(const s16x4*)(lds + i1);
  return __builtin_shufflevector(lo, hi, 0,1,2,3,4,5,6,7);
}

// ---------------------------------------------------------------------------
// weight convert+transpose: out[l][n][k] = bf16(in[l][k][n])
// ---------------------------------------------------------------------------
__global__ __launch_bounds__(256) void wtrans_kernel(
    const float* __restrict__ in, u16* __restrict__ out, int K, int N, int total)
{
  int idx = blockIdx.x*256 + threadIdx.x;
  if (idx >= total) return;
  int l = idx / (N*K);
  int r = idx - l*(N*K);
  int n = r / K;
  int k = r - n*K;
  out[idx] = f2bf(in[(size_t)l*K*N + (size_t)k*N + n]);
}

// ---------------------------------------------------------------------------
// embedding gather: h[b,s,:] = E[s, x[b,s], :]
// ---------------------------------------------------------------------------
__global__ __launch_bounds__(256) void embed_kernel(
    const int* __restrict__ x, const float* __restrict__ E, float* __restrict__ h)
{
  int t = threadIdx.x;
  int m = blockIdx.x*4 + (t>>6);
  int lane = t & 63;
  int s = m & 63;
  int tok = x[m];
  const float4 v = *(const float4*)(E + ((size_t)s*VOCAB + tok)*DMODEL + lane*4);
  *(float4*)(h + (size_t)m*DMODEL + lane*4) = v;
}

// ---------------------------------------------------------------------------
// LayerNorm (fp32 in, bf16 out). one wave per token row (D=256).
// ---------------------------------------------------------------------------
__global__ __launch_bounds__(256) void ln_kernel(
    const float* __restrict__ h, const float* __restrict__ gam,
    const float* __restrict__ bet, u16* __restrict__ out)
{
  int t = threadIdx.x;
  int m = blockIdx.x*4 + (t>>6);
  int lane = t & 63;
  const float4 v = *(const float4*)(h + (size_t)m*DMODEL + lane*4);
  float s = v.x+v.y+v.z+v.w;
  float q = v.x*v.x+v.y*v.y+v.z*v.z+v.w*v.w;
  #pragma unroll
  for (int mask=1; mask<64; mask<<=1){
    s += __shfl_xor(s, mask);
    q += __shfl_xor(q, mask);
  }
  float mean = s*(1.f/256.f);
  float var  = q*(1.f/256.f) - mean*mean;
  float rs   = rsqrtf(var + 1e-5f);
  const float4 gv = *(const float4*)(gam + lane*4);
  const float4 bv = *(const float4*)(bet + lane*4);
  ushort4 ov;
  ov.x = f2bf((v.x-mean)*rs*gv.x + bv.x);
  ov.y = f2bf((v.y-mean)*rs*gv.y + bv.y);
  ov.z = f2bf((v.z-mean)*rs*gv.z + bv.z);
  ov.w = f2bf((v.w-mean)*rs*gv.w + bv.w);
  *(ushort4*)(out + (size_t)m*DMODEL + lane*4) = ov;
}

// ---------------------------------------------------------------------------
// GEMM: 128x128 tile, BK=64, 4 waves (2x2), wave tile 64x64 (4x4 frags).
// MODE 0: bf16 out, no bias (QKV).  MODE 1: fp32 residual out += acc + bias.
// ---------------------------------------------------------------------------
template<int MODE>
__global__ __launch_bounds__(256, 2) void gemm_kernel(
    const u16* __restrict__ A, const u16* __restrict__ Bt,
    u16* __restrict__ outb, float* __restrict__ outf,
    const float* __restrict__ bias, int K, int N)
{
  __shared__ __align__(16) u16 As[128*64];
  __shared__ __align__(16) u16 Bs[128*64];
  const int t = threadIdx.x;
  const int w = t >> 6, lane = t & 63, g = lane >> 4, c = lane & 15;
  const int m0 = blockIdx.y * 128, n0 = blockIdx.x * 128;
  const int wm = (w >> 1) * 64, wn = (w & 1) * 64;

  f32x4 acc[4][4];
  #pragma unroll
  for (int i=0;i<4;++i)
    #pragma unroll
    for (int j=0;j<4;++j){ f32x4 z = {0.f,0.f,0.f,0.f}; acc[i][j] = z; }

  const int nkt = K >> 6;
  for (int kt = 0; kt < nkt; ++kt){
    #pragma unroll
    for (int i=0;i<4;++i){
      int cid = (i*4 + w)*64 + lane;
      int row = cid >> 3, seg = cid & 7;
      int col16 = (seg*8) ^ ((row&7)<<3);   // pre-swizzled k-offset (u16 units)
      gload16(A  + (size_t)(m0+row)*K + (size_t)kt*64 + col16, As + (i*4+w)*512);
      gload16(Bt + (size_t)(n0+row)*K + (size_t)kt*64 + col16, Bs + (i*4+w)*512);
    }
    asm volatile("s_waitcnt vmcnt(0)" ::: "memory");
    __syncthreads();

    #pragma unroll
    for (int kk=0; kk<2; ++kk){
      const int k0 = kk*32 + 4*g;
      s16x8 af[4];
      #pragma unroll
      for (int i=0;i<4;++i){
        int row = wm + i*16 + c;
        int sw = (row&7)<<3;
        af[i] = ldfrag(As, row*64 + (k0 ^ sw), row*64 + ((k0+16) ^ sw));
      }
      #pragma unroll
      for (int j=0;j<4;++j){
        int row = wn + j*16 + c;
        int sw = (row&7)<<3;
        s16x8 bf = ldfrag(Bs, row*64 + (k0 ^ sw), row*64 + ((k0+16) ^ sw));
        #pragma unroll
        for (int i=0;i<4;++i) acc[i][j] = mfma16(af[i], bf, acc[i][j]);
      }
    }
    __syncthreads();
  }

  #pragma unroll
  for (int i=0;i<4;++i){
    #pragma unroll
    for (int j=0;j<4;++j){
      int col = n0 + wn + j*16 + c;
      #pragma unroll
      for (int r=0;r<4;++r){
        int m = m0 + wm + i*16 + g*4 + r;
        if (MODE == 0){
          outb[(size_t)m*N + col] = f2bf(acc[i][j][r]);
        } else {
          float* p = outf + (size_t)m*N + col;
          *p += acc[i][j][r] + bias[col];
        }
      }
    }
  }
}

// ---------------------------------------------------------------------------
// Gated-FFN GEMM: computes a-panel (cols n0..) and g-panel (cols 1024+n0..)
// of u = n2@W1 + b1, then act = a * gelu_exact(g) -> bf16 [M,1024].
// ---------------------------------------------------------------------------
__global__ __launch_bounds__(256, 2) void gemm_gated_kernel(
    const u16* __restrict__ A, const u16* __restrict__ Bt,
    u16* __restrict__ act, const float* __restrict__ b1, int K)
{
  __shared__ __align__(16) u16 As[128*64];
  __shared__ __align__(16) u16 Ba[128*64];
  __shared__ __align__(16) u16 Bg[128*64];
  const int t = threadIdx.x;
  const int w = t >> 6, lane = t & 63, g = lane >> 4, c = lane & 15;
  const int m0 = blockIdx.y * 128, n0 = blockIdx.x * 128;
  const int wm = (w >> 1) * 64, wn = (w & 1) * 64;

  f32x4 acca[4][4], accg[4][4];
  #pragma unroll
  for (int i=0;i<4;++i)
    #pragma unroll
    for (int j=0;j<4;++j){ f32x4 z = {0.f,0.f,0.f,0.f}; acca[i][j] = z; accg[i][j] = z; }

  const int nkt = K >> 6;
  for (int kt = 0; kt < nkt; ++kt){
    #pragma unroll
    for (int i=0;i<4;++i){
      int cid = (i*4 + w)*64 + lane;
      int row = cid >> 3, seg = cid & 7;
      int col16 = (seg*8) ^ ((row&7)<<3);
      gload16(A  + (size_t)(m0+row)*K        + (size_t)kt*64 + col16, As + (i*4+w)*512);
      gload16(Bt + (size_t)(n0+row)*K        + (size_t)kt*64 + col16, Ba + (i*4+w)*512);
      gload16(Bt + (size_t)(1024+n0+row)*K   + (size_t)kt*64 + col16, Bg + (i*4+w)*512);
    }
    asm volatile("s_waitcnt vmcnt(0)" ::: "memory");
    __syncthreads();

    #pragma unroll
    for (int kk=0; kk<2; ++kk){
      const int k0 = kk*32 + 4*g;
      s16x8 af[4];
      #pragma unroll
      for (int i=0;i<4;++i){
        int row = wm + i*16 + c;
        int sw = (row&7)<<3;
        af[i] = ldfrag(As, row*64 + (k0 ^ sw), row*64 + ((k0+16) ^ sw));
      }
      #pragma unroll
      for (int j=0;j<4;++j){
        int row = wn + j*16 + c;
        int sw = (row&7)<<3;
        s16x8 bfa = ldfrag(Ba, row*64 + (k0 ^ sw), row*64 + ((k0+16) ^ sw));
        s16x8 bfg = ldfrag(Bg, row*64 + (k0 ^ sw), row*64 + ((k0+16) ^ sw));
        #pragma unroll
        for (int i=0;i<4;++i){
          acca[i][j] = mfma16(af[i], bfa, acca[i][j]);
          accg[i][j] = mfma16(af[i], bfg, accg[i][j]);
        }
      }
    }
    __syncthreads();
  }

  #pragma unroll
  for (int i=0;i<4;++i){
    #pragma unroll
    for (int j=0;j<4;++j){
      int col = n0 + wn + j*16 + c;
      float ba = b1[col], bg = b1[1024 + col];
      #pragma unroll
      for (int r=0;r<4;++r){
        int m = m0 + wm + i*16 + g*4 + r;
        float ua = acca[i][j][r] + ba;
        float ug = accg[i][j][r] + bg;
        float gel = 0.5f*ug*(1.0f + erff(ug*0.70710678118654752f));
        act[(size_t)m*FFDIM + col] = f2bf(ua*gel);
      }
    }
  }
}

// ---------------------------------------------------------------------------
// Attention: one block (4 waves) per (b,h). q,k,vt tiles (64x64) in padded
// LDS (stride 72). Each wave handles 16 q-rows: QK^T (MFMA) -> wave-parallel
// softmax (shfl_xor over 16-lane groups) -> P in LDS -> PV (MFMA).
// ---------------------------------------------------------------------------
__global__ __launch_bounds__(256) void attn_kernel(
    const u16* __restrict__ qkv, u16* __restrict__ o)
{
  __shared__ __align__(16) u16 qs[64*72];
  __shared__ __align__(16) u16 ks[64*72];
  __shared__ __align__(16) u16 vt[64*72];
  __shared__ __align__(16) u16 ps[4*16*72];
  const int t = threadIdx.x;
  const int w = t >> 6, lane = t & 63, g = lane >> 4, c = lane & 15;
  const int bh = blockIdx.x, b = bh >> 3, hh = bh & 7;
  const size_t qbase = (size_t)b*64*1536 + hh*64;

  #pragma unroll
  for (int i=0;i<2;++i){
    int cid = i*256 + t;
    int row = cid >> 3, seg = cid & 7;
    size_t go = qbase + (size_t)row*1536 + seg*8;
    *(uint4*)(&qs[row*72 + seg*8]) = *(const uint4*)(qkv + go);
    *(uint4*)(&ks[row*72 + seg*8]) = *(const uint4*)(qkv + go + 512);
    uint4 vv = *(const uint4*)(qkv + go + 1024);
    const u16* pv = (const u16*)&vv;
    #pragma unroll
    for (int j=0;j<8;++j) vt[(seg*8+j)*72 + row] = pv[j];
  }
  __syncthreads();

  // ---- scores: S[16x64] = q_wave @ k^T
  f32x4 accS[4];
  #pragma unroll
  for (int nf=0;nf<4;++nf){ f32x4 z = {0.f,0.f,0.f,0.f}; accS[nf] = z; }
  const int arow = w*16 + c;
  #pragma unroll
  for (int kk=0;kk<2;++kk){
    int k0 = kk*32 + 4*g;
    s16x8 a = ldfrag(qs, arow*72 + k0, arow*72 + k0 + 16);
    #pragma unroll
    for (int nf=0;nf<4;++nf){
      int brow = nf*16 + c;
      s16x8 bb = ldfrag(ks, brow*72 + k0, brow*72 + k0 + 16);
      accS[nf] = mfma16(a, bb, accS[nf]);
    }
  }

  // ---- softmax over 64 keys per q-row, write P (bf16) to per-wave LDS
  u16* pw = ps + w*16*72;
  #pragma unroll
  for (int r=0;r<4;++r){
    float mx = fmaxf(fmaxf(accS[0][r],accS[1][r]), fmaxf(accS[2][r],accS[3][r]));
    #pragma unroll
    for (int mask=1; mask<16; mask<<=1) mx = fmaxf(mx, __shfl_xor(mx, mask));
    float p0 = expf((accS[0][r]-mx)*0.125f);
    float p1 = expf((accS[1][r]-mx)*0.125f);
    float p2 = expf((accS[2][r]-mx)*0.125f);
    float p3 = expf((accS[3][r]-mx)*0.125f);
    float sm = p0+p1+p2+p3;
    #pragma unroll
    for (int mask=1; mask<16; mask<<=1) sm += __shfl_xor(sm, mask);
    float inv = 1.f/sm;
    pw[(g*4+r)*72 +  0 + c] = f2bf(p0*inv);
    pw[(g*4+r)*72 + 16 + c] = f2bf(p1*inv);
    pw[(g*4+r)*72 + 32 + c] = f2bf(p2*inv);
    pw[(g*4+r)*72 + 48 + c] = f2bf(p3*inv);
  }
  __syncthreads();

  // ---- PV: o[16x64] = P @ V   (A = P, Bt = V^T)
  f32x4 accO[4];
  #pragma unroll
  for (int nf=0;nf<4;++nf){ f32x4 z = {0.f,0.f,0.f,0.f}; accO[nf] = z; }
  #pragma unroll
  for (int kk=0;kk<2;++kk){
    int k0 = kk*32 + 4*g;
    s16x8 a = ldfrag(pw, c*72 + k0, c*72 + k0 + 16);
    #pragma unroll
    for (int nf=0;nf<4;++nf){
      s16x8 bb = ldfrag(vt, (nf*16+c)*72 + k0, (nf*16+c)*72 + k0 + 16);
      accO[nf] = mfma16(a, bb, accO[nf]);
    }
  }

  #pragma unroll
  for (int nf=0;nf<4;++nf){
    #pragma unroll
    for (int r=0;r<4;++r){
      int q = w*16 + g*4 + r;
      o[(size_t)(b*64 + q)*INNERD + hh*64 + nf*16 + c] = f2bf(accO[nf][r]);
    }
  }
}

// ---------------------------------------------------------------------------
extern "C" void kernel_launch(void* const* d_in, const int* in_sizes, int n_in,
                              void* d_out, int out_size, void* d_ws, size_t ws_size,
                              hipStream_t stream)
{
  const int*   x    = (const int*)  d_in[0];
  const float* E    = (const float*)d_in[1];
  const float* ln1g = (const float*)d_in[2];
  const float* ln1b = (const float*)d_in[3];
  const float* Wqkv = (const float*)d_in[4];
  const float* Wout = (const float*)d_in[5];
  const float* bout = (const float*)d_in[6];
  const float* ln2g = (const float*)d_in[7];
  const float* ln2b = (const float*)d_in[8];
  const float* W1   = (const float*)d_in[9];
  const float* b1   = (const float*)d_in[10];
  const float* W2   = (const float*)d_in[11];
  const float* b2   = (const float*)d_in[12];
  float* h = (float*)d_out;

  // embedding first: even if workspace is too small, output is not all-zero
  embed_kernel<<<MTOK/4,256,0,stream>>>(x, E, h);

  // ---- workspace layout: bf16 weights (15.7 MB) + chunked activations
  const size_t WQKV = (size_t)LAYERS*1536*256;
  const size_t WOUT = (size_t)LAYERS*256*512;
  const size_t W1T  = (size_t)LAYERS*2048*256;
  const size_t W2T  = (size_t)LAYERS*256*1024;
  u16* wqkv_t = (u16*)d_ws;
  u16* wout_t = wqkv_t + WQKV;
  u16* w1_t   = wout_t + WOUT;
  u16* w2_t   = w1_t   + W1T;
  u16* abase  = w2_t   + W2T;
  const size_t wbytes = (WQKV + WOUT + W1T + W2T) * 2;
  if (ws_size < wbytes + (size_t)1024*4608) return;  // hopeless (<21 MB)
  size_t rem = ws_size - wbytes;

  // pick largest chunk Mc (tokens, multiple of 1024) with Mc*4608 B of bufs
  int Mc = MTOK;
  while (Mc > 1024 && (size_t)Mc*4608 > rem) Mc >>= 1;
  const int nc = MTOK / Mc;

  u16* n_bf   = abase;                       // [Mc][256]
  u16* o_bf   = n_bf + (size_t)Mc*256;       // [Mc][512]
  u16* qkv_bf = o_bf + (size_t)Mc*512;       // [Mc][1536]
  u16* act_bf = qkv_bf;                      // [Mc][1024] aliases qkv

  int tot;
  tot = LAYERS*1536*256; wtrans_kernel<<<(tot+255)/256,256,0,stream>>>(Wqkv, wqkv_t, 256,  1536, tot);
  tot = LAYERS*256*512;  wtrans_kernel<<<(tot+255)/256,256,0,stream>>>(Wout, wout_t, 512,  256,  tot);
  tot = LAYERS*2048*256; wtrans_kernel<<<(tot+255)/256,256,0,stream>>>(W1,   w1_t,   256,  2048, tot);
  tot = LAYERS*256*1024; wtrans_kernel<<<(tot+255)/256,256,0,stream>>>(W2,   w2_t,   1024, 256,  tot);

  for (int l=0; l<LAYERS; ++l){
    for (int cidx=0; cidx<nc; ++cidx){
      float* hc = h + (size_t)cidx*Mc*256;
      ln_kernel<<<Mc/4,256,0,stream>>>(hc, ln1g + l*256, ln1b + l*256, n_bf);
      gemm_kernel<0><<<dim3(1536/128, Mc/128),256,0,stream>>>(
          n_bf, wqkv_t + (size_t)l*1536*256, qkv_bf, nullptr, nullptr, 256, 1536);
      attn_kernel<<<(Mc/64)*NHEAD,256,0,stream>>>(qkv_bf, o_bf);
      gemm_kernel<1><<<dim3(256/128, Mc/128),256,0,stream>>>(
          o_bf, wout_t + (size_t)l*256*512, nullptr, hc, bout + l*256, 512, 256);
      ln_kernel<<<Mc/4,256,0,stream>>>(hc, ln2g + l*256, ln2b + l*256, n_bf);
      gemm_gated_kernel<<<dim3(1024/128, Mc/128),256,0,stream>>>(
          n_bf, w1_t + (size_t)l*2048*256, act_bf, b1 + l*2048, 256);
      gemm_kernel<1><<<dim3(256/128, Mc/128),256,0,stream>>>(
          act_bf, w2_t + (size_t)l*256*1024, nullptr, hc, b2 + l*256, 1024, 256);
    }
  }
}

// Round 3
// 4503.450 us; speedup vs baseline: 1.3372x; 1.3372x over previous
//
#include <hip/hip_runtime.h>
#include <stdint.h>
#include <math.h>

// ---------------------------------------------------------------------------
// Transformer forward, MI355X. bf16 MFMA operands, fp32 accum, fp32 residual.
// GEMM: C[M,N] = A[M,K] x Bt[N,K]^T, both K-major bf16.
// K-dim of all GEMM inputs is stored PERMUTED within each 32-block:
//   k = 32*kk + 16*hi + 4*g + o  ->  p = 32*kk + 8*g + 4*hi + o
// so one MFMA fragment (k = {4g..4g+3, 16+4g..16+4g+3} of a 32-half) is one
// contiguous 16B chunk -> single ds_read_b128. Chunks XOR-swizzled by row&7
// (applied on the pre-swizzled global source; LDS dest stays linear for
// global_load_lds). Producers (wtrans + all activation epilogues) write the
// permuted layout; qkv_bf (consumed by attn, not a GEMM A/B) stays standard.
// T1 chunked XCD swizzle on tiled GEMMs. LN fused into residual GEMMs.
// ---------------------------------------------------------------------------

#define LAYERS 6
#define BATCH  2048
#define SEQ    64
#define DMODEL 256
#define NHEAD  8
#define INNERD 512
#define FFDIM  1024
#define VOCAB  100
#define MTOK   (BATCH*SEQ)

typedef unsigned short u16;
typedef __attribute__((ext_vector_type(4))) float f32x4;
typedef __attribute__((ext_vector_type(4))) short s16x4;
typedef __attribute__((ext_vector_type(8))) short s16x8;

__device__ inline u16 f2bf(float f){
  union { float f; unsigned int u; } x; x.f = f;
  unsigned int u = x.u;
  return (u16)((u + 0x7fffu + ((u >> 16) & 1u)) >> 16);
}

__device__ inline void gload16(const void* g, void* l){
  __builtin_amdgcn_global_load_lds(
      (const __attribute__((address_space(1))) unsigned int*)g,
      (__attribute__((address_space(3))) unsigned int*)l, 16, 0, 0);
}

__device__ inline f32x4 mfma16(s16x8 a, s16x8 b, f32x4 c){
  return __builtin_amdgcn_mfma_f32_16x16x32_bf16(a, b, c, 0, 0, 0);
}

// fragment = one 16B chunk (permuted layout), single ds_read_b128
__device__ inline s16x8 ldfrag(const u16* lds, int row, int kk, int g){
  int chunk = ((kk<<2)|g) ^ (row&7);
  return *(const s16x8*)(lds + row*64 + chunk*8);
}

// permuted column index for within-32-block k remap (writers)
__device__ inline int pcol32(int col_base32, int hi, int g, int o){
  return col_base32 | (g<<3) | (hi<<2) | o;
}

// ---------------------------------------------------------------------------
// weight convert+transpose+permute: out[l][n][p(k)] = bf16(in[l][k][n])
// ---------------------------------------------------------------------------
__global__ __launch_bounds__(256) void wtrans_kernel(
    const float* __restrict__ in, u16* __restrict__ out, int K, int N, int total)
{
  int idx = blockIdx.x*256 + threadIdx.x;
  if (idx >= total) return;
  int l = idx / (N*K);
  int r = idx - l*(N*K);
  int n = r / K;
  int k = r - n*K;
  int p = (k & ~31) | (((k>>2)&3)<<3) | (((k>>4)&1)<<2) | (k&3);
  out[(size_t)l*N*K + (size_t)n*K + p] = f2bf(in[(size_t)l*K*N + (size_t)k*N + n]);
}

// ---------------------------------------------------------------------------
// embed + ln1[0]: h = E-gather (fp32, standard), n = LN(h) (bf16, permuted)
// ---------------------------------------------------------------------------
__global__ __launch_bounds__(256) void embed_ln_kernel(
    const int* __restrict__ x, const float* __restrict__ E,
    const float* __restrict__ gam, const float* __restrict__ bet,
    float* __restrict__ h, u16* __restrict__ nout)
{
  int t = threadIdx.x;
  int m = blockIdx.x*4 + (t>>6);
  int lane = t & 63;
  int s = m & 63;
  int tok = x[m];
  const float4 v = *(const float4*)(E + ((size_t)s*VOCAB + tok)*DMODEL + lane*4);
  *(float4*)(h + (size_t)m*DMODEL + lane*4) = v;
  float su = v.x+v.y+v.z+v.w;
  float q  = v.x*v.x+v.y*v.y+v.z*v.z+v.w*v.w;
  #pragma unroll
  for (int mask=1; mask<64; mask<<=1){
    su += __shfl_xor(su, mask);
    q  += __shfl_xor(q,  mask);
  }
  float mean = su*(1.f/256.f);
  float var  = q*(1.f/256.f) - mean*mean;
  float rs   = rsqrtf(var + 1e-5f);
  const float4 gv = *(const float4*)(gam + lane*4);
  const float4 bv = *(const float4*)(bet + lane*4);
  ushort4 ov;
  ov.x = f2bf((v.x-mean)*rs*gv.x + bv.x);
  ov.y = f2bf((v.y-mean)*rs*gv.y + bv.y);
  ov.z = f2bf((v.z-mean)*rs*gv.z + bv.z);
  ov.w = f2bf((v.w-mean)*rs*gv.w + bv.w);
  int p4 = (lane>>3)*32 + (lane&3)*8 + ((lane>>2)&1)*4;   // permuted base
  *(ushort4*)(nout + (size_t)m*DMODEL + p4) = ov;
}

// ---------------------------------------------------------------------------
// QKV GEMM: 128x128 tile, BK=64, 4 waves 2x2. bf16 standard-layout output.
// 1D grid, T1 chunked XCD swizzle, x = wg % NXB (same A-panel contiguous).
// ---------------------------------------------------------------------------
__global__ __launch_bounds__(256, 2) void gemm_qkv_kernel(
    const u16* __restrict__ A, const u16* __restrict__ Bt,
    u16* __restrict__ outb, int K, int N)
{
  __shared__ __align__(16) u16 As[128*64];
  __shared__ __align__(16) u16 Bs[128*64];
  const int t = threadIdx.x;
  const int w = t >> 6, lane = t & 63, g = lane >> 4, c = lane & 15;
  const int nxb = N >> 7;
  const int cpx = gridDim.x >> 3;
  const int wg = (blockIdx.x & 7)*cpx + (blockIdx.x >> 3);
  const int n0 = (wg % nxb) * 128, m0 = (wg / nxb) * 128;
  const int wm = (w >> 1) * 64, wn = (w & 1) * 64;

  f32x4 acc[4][4];
  #pragma unroll
  for (int i=0;i<4;++i)
    #pragma unroll
    for (int j=0;j<4;++j){ f32x4 z = {0.f,0.f,0.f,0.f}; acc[i][j] = z; }

  const int nkt = K >> 6;
  for (int kt = 0; kt < nkt; ++kt){
    #pragma unroll
    for (int i=0;i<4;++i){
      int cid = (i*4 + w)*64 + lane;
      int row = cid >> 3, qs = cid & 7;
      int col16 = ((qs ^ (row&7))<<3);
      gload16(A  + (size_t)(m0+row)*K + (size_t)kt*64 + col16, As + (i*4+w)*512);
      gload16(Bt + (size_t)(n0+row)*K + (size_t)kt*64 + col16, Bs + (i*4+w)*512);
    }
    asm volatile("s_waitcnt vmcnt(0)" ::: "memory");
    __syncthreads();
    #pragma unroll
    for (int kk=0; kk<2; ++kk){
      s16x8 af[4];
      #pragma unroll
      for (int i=0;i<4;++i) af[i] = ldfrag(As, wm + i*16 + c, kk, g);
      #pragma unroll
      for (int j=0;j<4;++j){
        s16x8 bf = ldfrag(Bs, wn + j*16 + c, kk, g);
        #pragma unroll
        for (int i=0;i<4;++i) acc[i][j] = mfma16(af[i], bf, acc[i][j]);
      }
    }
    __syncthreads();
  }

  #pragma unroll
  for (int i=0;i<4;++i)
    #pragma unroll
    for (int j=0;j<4;++j){
      int col = n0 + wn + j*16 + c;
      #pragma unroll
      for (int r=0;r<4;++r){
        int m = m0 + wm + i*16 + g*4 + r;
        outb[(size_t)m*N + col] = f2bf(acc[i][j][r]);
      }
    }
}

// ---------------------------------------------------------------------------
// Gated-FFN GEMM (K=256): a/g panels, act = a * gelu(g), permuted bf16 store.
// ---------------------------------------------------------------------------
__global__ __launch_bounds__(256, 2) void gemm_gated_kernel(
    const u16* __restrict__ A, const u16* __restrict__ Bt,
    u16* __restrict__ act, const float* __restrict__ b1, int K)
{
  __shared__ __align__(16) u16 As[128*64];
  __shared__ __align__(16) u16 Ba[128*64];
  __shared__ __align__(16) u16 Bg[128*64];
  const int t = threadIdx.x;
  const int w = t >> 6, lane = t & 63, g = lane >> 4, c = lane & 15;
  const int cpx = gridDim.x >> 3;
  const int wg = (blockIdx.x & 7)*cpx + (blockIdx.x >> 3);
  const int n0 = (wg & 7) * 128, m0 = (wg >> 3) * 128;
  const int wm = (w >> 1) * 64, wn = (w & 1) * 64;

  f32x4 acca[4][4], accg[4][4];
  #pragma unroll
  for (int i=0;i<4;++i)
    #pragma unroll
    for (int j=0;j<4;++j){ f32x4 z = {0.f,0.f,0.f,0.f}; acca[i][j] = z; accg[i][j] = z; }

  const int nkt = K >> 6;
  for (int kt = 0; kt < nkt; ++kt){
    #pragma unroll
    for (int i=0;i<4;++i){
      int cid = (i*4 + w)*64 + lane;
      int row = cid >> 3, qs = cid & 7;
      int col16 = ((qs ^ (row&7))<<3);
      gload16(A  + (size_t)(m0+row)*K      + (size_t)kt*64 + col16, As + (i*4+w)*512);
      gload16(Bt + (size_t)(n0+row)*K      + (size_t)kt*64 + col16, Ba + (i*4+w)*512);
      gload16(Bt + (size_t)(1024+n0+row)*K + (size_t)kt*64 + col16, Bg + (i*4+w)*512);
    }
    asm volatile("s_waitcnt vmcnt(0)" ::: "memory");
    __syncthreads();
    #pragma unroll
    for (int kk=0; kk<2; ++kk){
      s16x8 af[4];
      #pragma unroll
      for (int i=0;i<4;++i) af[i] = ldfrag(As, wm + i*16 + c, kk, g);
      #pragma unroll
      for (int j=0;j<4;++j){
        int row = wn + j*16 + c;
        s16x8 bfa = ldfrag(Ba, row, kk, g);
        s16x8 bfg = ldfrag(Bg, row, kk, g);
        #pragma unroll
        for (int i=0;i<4;++i){
          acca[i][j] = mfma16(af[i], bfa, acca[i][j]);
          accg[i][j] = mfma16(af[i], bfg, accg[i][j]);
        }
      }
    }
    __syncthreads();
  }

  #pragma unroll
  for (int i=0;i<4;++i)
    #pragma unroll
    for (int j=0;j<4;++j){
      int col = n0 + wn + j*16 + c;
      int pc = pcol32(col & ~31, j&1, c>>2, c&3);
      float ba = b1[col], bg = b1[1024 + col];
      #pragma unroll
      for (int r=0;r<4;++r){
        int m = m0 + wm + i*16 + g*4 + r;
        float ua = acca[i][j][r] + ba;
        float ug = accg[i][j][r] + bg;
        float gel = 0.5f*ug*(1.0f + erff(ug*0.70710678118654752f));
        act[(size_t)m*FFDIM + pc] = f2bf(ua*gel);
      }
    }
}

// ---------------------------------------------------------------------------
// Residual GEMM + LN fusion: tile 128 x 256 (full N), 4 waves 2x2 (64x128).
// h[m] += acc + bias; if DO_LN: n = LN(h)*gam+bet (bf16, permuted).
// ---------------------------------------------------------------------------
template<int DO_LN>
__global__ __launch_bounds__(256, 2) void gemm_res_ln_kernel(
    const u16* __restrict__ A, const u16* __restrict__ Bt,
    float* __restrict__ h, const float* __restrict__ bias,
    const float* __restrict__ gam, const float* __restrict__ bet,
    u16* __restrict__ nout, int K)
{
  __shared__ __align__(16) u16 As[128*64];
  __shared__ __align__(16) u16 Bs[256*64];
  __shared__ float ps[128][4];
  const int t = threadIdx.x;
  const int w = t >> 6, lane = t & 63, g = lane >> 4, c = lane & 15;
  const int wr = w >> 1, wc = w & 1;
  const int m0 = blockIdx.x * 128;

  f32x4 acc[4][8];
  #pragma unroll
  for (int i=0;i<4;++i)
    #pragma unroll
    for (int j=0;j<8;++j){ f32x4 z = {0.f,0.f,0.f,0.f}; acc[i][j] = z; }

  const int nkt = K >> 6;
  for (int kt = 0; kt < nkt; ++kt){
    #pragma unroll
    for (int i=0;i<4;++i){            // A: 128 rows x 8 chunks
      int cid = (i*4 + w)*64 + lane;
      int row = cid >> 3, qs = cid & 7;
      gload16(A + (size_t)(m0+row)*K + (size_t)kt*64 + ((qs ^ (row&7))<<3),
              As + (i*4+w)*512);
    }
    #pragma unroll
    for (int i=0;i<8;++i){            // B: 256 rows x 8 chunks
      int cid = (i*4 + w)*64 + lane;
      int row = cid >> 3, qs = cid & 7;
      gload16(Bt + (size_t)row*K + (size_t)kt*64 + ((qs ^ (row&7))<<3),
              Bs + (i*4+w)*512);
    }
    asm volatile("s_waitcnt vmcnt(0)" ::: "memory");
    __syncthreads();
    #pragma unroll
    for (int kk=0; kk<2; ++kk){
      s16x8 af[4];
      #pragma unroll
      for (int i=0;i<4;++i) af[i] = ldfrag(As, wr*64 + i*16 + c, kk, g);
      #pragma unroll
      for (int j=0;j<8;++j){
        s16x8 bf = ldfrag(Bs, wc*128 + j*16 + c, kk, g);
        #pragma unroll
        for (int i=0;i<4;++i) acc[i][j] = mfma16(af[i], bf, acc[i][j]);
      }
    }
    __syncthreads();
  }

  // pass 1: residual add, h store, per-row partial sums -> LDS
  #pragma unroll
  for (int i=0;i<4;++i){
    #pragma unroll
    for (int r=0;r<4;++r){
      int rl = wr*64 + i*16 + g*4 + r;
      size_t mrow = (size_t)(m0 + rl)*DMODEL;
      float s = 0.f, q2 = 0.f;
      #pragma unroll
      for (int j=0;j<8;++j){
        int col = wc*128 + j*16 + c;
        float v = acc[i][j][r] + bias[col] + h[mrow + col];
        h[mrow + col] = v;
        s += v; q2 += v*v;
      }
      if (DO_LN){
        #pragma unroll
        for (int mask=1; mask<16; mask<<=1){
          s  += __shfl_xor(s,  mask);
          q2 += __shfl_xor(q2, mask);
        }
        if (c == 0){ ps[rl][wc*2] = s; ps[rl][wc*2+1] = q2; }
      }
    }
  }
  if (DO_LN){
    __syncthreads();
    #pragma unroll
    for (int i=0;i<4;++i){
      #pragma unroll
      for (int r=0;r<4;++r){
        int rl = wr*64 + i*16 + g*4 + r;
        size_t mrow = (size_t)(m0 + rl)*DMODEL;
        float st = ps[rl][0] + ps[rl][2];
        float qt = ps[rl][1] + ps[rl][3];
        float mean = st*(1.f/256.f);
        float var  = qt*(1.f/256.f) - mean*mean;
        float rs   = rsqrtf(var + 1e-5f);
        #pragma unroll
        for (int j=0;j<8;++j){
          int col = wc*128 + j*16 + c;
          float v = h[mrow + col];
          int pc = pcol32(col & ~31, j&1, c>>2, c&3);
          nout[mrow + pc] = f2bf((v-mean)*rs*gam[col] + bet[col]);
        }
      }
    }
  }
}

// ---------------------------------------------------------------------------
// Attention: one block per (b,h). Permuted bf16 o-store.
// ---------------------------------------------------------------------------
__global__ __launch_bounds__(256) void attn_kernel(
    const u16* __restrict__ qkv, u16* __restrict__ o)
{
  __shared__ __align__(16) u16 qs[64*72];
  __shared__ __align__(16) u16 ks[64*72];
  __shared__ __align__(16) u16 vt[64*72];
  __shared__ __align__(16) u16 psm[4*16*72];
  const int t = threadIdx.x;
  const int w = t >> 6, lane = t & 63, g = lane >> 4, c = lane & 15;
  const int bh = blockIdx.x, b = bh >> 3, hh = bh & 7;
  const size_t qbase = (size_t)b*64*1536 + hh*64;

  #pragma unroll
  for (int i=0;i<2;++i){
    int cid = i*256 + t;
    int row = cid >> 3, seg = cid & 7;
    size_t go = qbase + (size_t)row*1536 + seg*8;
    *(uint4*)(&qs[row*72 + seg*8]) = *(const uint4*)(qkv + go);
    *(uint4*)(&ks[row*72 + seg*8]) = *(const uint4*)(qkv + go + 512);
    uint4 vv = *(const uint4*)(qkv + go + 1024);
    const u16* pv = (const u16*)&vv;
    #pragma unroll
    for (int j=0;j<8;++j) vt[(seg*8+j)*72 + row] = pv[j];
  }
  __syncthreads();

  f32x4 accS[4];
  #pragma unroll
  for (int nf=0;nf<4;++nf){ f32x4 z = {0.f,0.f,0.f,0.f}; accS[nf] = z; }
  const int arow = w*16 + c;
  #pragma unroll
  for (int kk=0;kk<2;++kk){
    int k0 = kk*32 + 4*g;
    s16x4 alo = *(const s16x4*)(qs + arow*72 + k0);
    s16x4 ahi = *(const s16x4*)(qs + arow*72 + k0 + 16);
    s16x8 a = __builtin_shufflevector(alo, ahi, 0,1,2,3,4,5,6,7);
    #pragma unroll
    for (int nf=0;nf<4;++nf){
      int brow = nf*16 + c;
      s16x4 blo = *(const s16x4*)(ks + brow*72 + k0);
      s16x4 bhi = *(const s16x4*)(ks + brow*72 + k0 + 16);
      s16x8 bb = __builtin_shufflevector(blo, bhi, 0,1,2,3,4,5,6,7);
      accS[nf] = mfma16(a, bb, accS[nf]);
    }
  }

  u16* pw = psm + w*16*72;
  #pragma unroll
  for (int r=0;r<4;++r){
    float mx = fmaxf(fmaxf(accS[0][r],accS[1][r]), fmaxf(accS[2][r],accS[3][r]));
    #pragma unroll
    for (int mask=1; mask<16; mask<<=1) mx = fmaxf(mx, __shfl_xor(mx, mask));
    float p0 = expf((accS[0][r]-mx)*0.125f);
    float p1 = expf((accS[1][r]-mx)*0.125f);
    float p2 = expf((accS[2][r]-mx)*0.125f);
    float p3 = expf((accS[3][r]-mx)*0.125f);
    float sm = p0+p1+p2+p3;
    #pragma unroll
    for (int mask=1; mask<16; mask<<=1) sm += __shfl_xor(sm, mask);
    float inv = 1.f/sm;
    pw[(g*4+r)*72 +  0 + c] = f2bf(p0*inv);
    pw[(g*4+r)*72 + 16 + c] = f2bf(p1*inv);
    pw[(g*4+r)*72 + 32 + c] = f2bf(p2*inv);
    pw[(g*4+r)*72 + 48 + c] = f2bf(p3*inv);
  }
  __syncthreads();

  f32x4 accO[4];
  #pragma unroll
  for (int nf=0;nf<4;++nf){ f32x4 z = {0.f,0.f,0.f,0.f}; accO[nf] = z; }
  #pragma unroll
  for (int kk=0;kk<2;++kk){
    int k0 = kk*32 + 4*g;
    s16x4 alo = *(const s16x4*)(pw + c*72 + k0);
    s16x4 ahi = *(const s16x4*)(pw + c*72 + k0 + 16);
    s16x8 a = __builtin_shufflevector(alo, ahi, 0,1,2,3,4,5,6,7);
    #pragma unroll
    for (int nf=0;nf<4;++nf){
      int brow = nf*16 + c;
      s16x4 blo = *(const s16x4*)(vt + brow*72 + k0);
      s16x4 bhi = *(const s16x4*)(vt + brow*72 + k0 + 16);
      s16x8 bb = __builtin_shufflevector(blo, bhi, 0,1,2,3,4,5,6,7);
      accO[nf] = mfma16(a, bb, accO[nf]);
    }
  }

  #pragma unroll
  for (int nf=0;nf<4;++nf){
    #pragma unroll
    for (int r=0;r<4;++r){
      int q = w*16 + g*4 + r;
      int col = hh*64 + nf*16 + c;
      int pc = pcol32(col & ~31, nf&1, c>>2, c&3);
      o[(size_t)(b*64 + q)*INNERD + pc] = f2bf(accO[nf][r]);
    }
  }
}

// ---------------------------------------------------------------------------
extern "C" void kernel_launch(void* const* d_in, const int* in_sizes, int n_in,
                              void* d_out, int out_size, void* d_ws, size_t ws_size,
                              hipStream_t stream)
{
  const int*   x    = (const int*)  d_in[0];
  const float* E    = (const float*)d_in[1];
  const float* ln1g = (const float*)d_in[2];
  const float* ln1b = (const float*)d_in[3];
  const float* Wqkv = (const float*)d_in[4];
  const float* Wout = (const float*)d_in[5];
  const float* bout = (const float*)d_in[6];
  const float* ln2g = (const float*)d_in[7];
  const float* ln2b = (const float*)d_in[8];
  const float* W1   = (const float*)d_in[9];
  const float* b1   = (const float*)d_in[10];
  const float* W2   = (const float*)d_in[11];
  const float* b2   = (const float*)d_in[12];
  float* h = (float*)d_out;

  const size_t WQKV = (size_t)LAYERS*1536*256;
  const size_t WOUT = (size_t)LAYERS*256*512;
  const size_t W1T  = (size_t)LAYERS*2048*256;
  const size_t W2T  = (size_t)LAYERS*256*1024;
  u16* wqkv_t = (u16*)d_ws;
  u16* wout_t = wqkv_t + WQKV;
  u16* w1_t   = wout_t + WOUT;
  u16* w2_t   = w1_t   + W1T;
  u16* abase  = w2_t   + W2T;
  const size_t wbytes = (WQKV + WOUT + W1T + W2T) * 2;
  if (ws_size < wbytes + (size_t)1024*4608) return;
  size_t rem = ws_size - wbytes;

  int Mc = MTOK;
  while (Mc > 1024 && (size_t)Mc*4608 > rem) Mc >>= 1;
  const int nc = MTOK / Mc;

  u16* n_bf   = abase;                       // [Mc][256]  permuted
  u16* o_bf   = n_bf + (size_t)Mc*256;       // [Mc][512]  permuted
  u16* qkv_bf = o_bf + (size_t)Mc*512;       // [Mc][1536] standard
  u16* act_bf = qkv_bf;                      // [Mc][1024] permuted (aliases)

  int tot;
  tot = LAYERS*1536*256; wtrans_kernel<<<(tot+255)/256,256,0,stream>>>(Wqkv, wqkv_t, 256,  1536, tot);
  tot = LAYERS*256*512;  wtrans_kernel<<<(tot+255)/256,256,0,stream>>>(Wout, wout_t, 512,  256,  tot);
  tot = LAYERS*2048*256; wtrans_kernel<<<(tot+255)/256,256,0,stream>>>(W1,   w1_t,   256,  2048, tot);
  tot = LAYERS*256*1024; wtrans_kernel<<<(tot+255)/256,256,0,stream>>>(W2,   w2_t,   1024, 256,  tot);

  for (int cidx=0; cidx<nc; ++cidx){
    float* hc = h + (size_t)cidx*Mc*256;
    const int* xc = x + (size_t)cidx*Mc;
    embed_ln_kernel<<<Mc/4,256,0,stream>>>(xc, E, ln1g, ln1b, hc, n_bf);
    for (int l=0; l<LAYERS; ++l){
      gemm_qkv_kernel<<<12*(Mc/128),256,0,stream>>>(
          n_bf, wqkv_t + (size_t)l*1536*256, qkv_bf, 256, 1536);
      attn_kernel<<<(Mc/64)*NHEAD,256,0,stream>>>(qkv_bf, o_bf);
      gemm_res_ln_kernel<1><<<Mc/128,256,0,stream>>>(
          o_bf, wout_t + (size_t)l*256*512, hc, bout + l*256,
          ln2g + l*256, ln2b + l*256, n_bf, 512);
      gemm_gated_kernel<<<8*(Mc/128),256,0,stream>>>(
          n_bf, w1_t + (size_t)l*2048*256, act_bf, b1 + l*2048, 256);
      if (l < LAYERS-1){
        gemm_res_ln_kernel<1><<<Mc/128,256,0,stream>>>(
            act_bf, w2_t + (size_t)l*256*1024, hc, b2 + l*256,
            ln1g + (l+1)*256, ln1b + (l+1)*256, n_bf, 1024);
      } else {
        gemm_res_ln_kernel<0><<<Mc/128,256,0,stream>>>(
            act_bf, w2_t + (size_t)l*256*1024, hc, b2 + l*256,
            nullptr, nullptr, nullptr, 1024);
      }
    }
  }
}